// Round 5
// baseline (79.003 us; speedup 1.0000x reference)
//
#include <hip/hip_runtime.h>
#include <hip/hip_cooperative_groups.h>
#include <math.h>
#include <stdint.h>

namespace cg = cooperative_groups;

// MMCE: sum_{i,j} v_i v_j exp(-|p_i - p_j| / 0.4) / N^2
//   p_i = max softmax prob of row i, v_i = (argmax_i == target_i) - p_i.
// a_i = v_i e^{-p_i/bw}, b_i = v_i e^{+p_i/bw};
// pair term = med3(a_i*b_j, b_i*a_j, 0): both products share the sign of
// v_i*v_j; med3 picks min if positive, max if negative -- exactly
// v_i v_j e^{-|p_i-p_j|/bw}. 4 VALU/pair, branch-free.
//
// R4 lesson: hipLaunchCooperativeKernel silently rejects grids that exceed
// the runtime's co-residency estimate. Grid is now clamped by the occupancy
// API on the host, and both phases are persistent-grid loops (correct for
// ANY grid >= 1).

static constexpr float KBW_INV = 2.5f;           // 1/0.4
static constexpr double FXSCALE = 1073741824.0;  // 2^30 fixed-point

#define TPB 256
#define RPW 2      // rows per wave per group-iteration: 32 VGPR payload
#define GROUP 8    // rows per block per group-iteration (4 waves * RPW)
#define JBLK 64    // j-rows staged per tile
#define ICHUNK 1024  // i-rows per tile (IPT * TPB)
#define IPT 4
// Work decomposition (grid-independent):
//   phase 1: N/GROUP = 1024 row-groups
//   phase 2: (N/ICHUNK) * (N/JBLK) = 8 * 128 = 1024 tiles

__global__ __launch_bounds__(TPB) void mmce_fused(
    const float* __restrict__ inp, const int* __restrict__ tgt,
    float2* __restrict__ AB, unsigned long long* __restrict__ acc,
    unsigned int* __restrict__ counter, float* __restrict__ out,
    int N, int C, int nBlocks) {
  const int tid = threadIdx.x;
  const int wv = tid >> 6;
  const int lane = tid & 63;

  if (blockIdx.x == 0 && tid == 0) { *acc = 0ull; *counter = 0u; }

  // ---------------- Phase 1: per-row stats, persistent over row-groups ------
  const int C4 = C >> 2;  // 250 float4 per row
  const int nGroups = N / GROUP;

  for (int g = blockIdx.x; g < nGroups; g += gridDim.x) {
    const int rowbase = g * GROUP + wv * RPW;

    float4 x[RPW][4];
    #pragma unroll
    for (int r = 0; r < RPW; ++r) {
      const float4* rp =
          reinterpret_cast<const float4*>(inp + (size_t)(rowbase + r) * C);
      #pragma unroll
      for (int w = 0; w < 4; ++w) {
        const int k = lane + w * 64;
        x[r][w] = (k < C4)
                      ? rp[k]
                      : make_float4(-INFINITY, -INFINITY, -INFINITY, -INFINITY);
      }
    }

    float m[RPW];
    int am[RPW];
    #pragma unroll
    for (int r = 0; r < RPW; ++r) {
      m[r] = -INFINITY;
      am[r] = 0x7fffffff;
      #pragma unroll
      for (int w = 0; w < 4; ++w) {
        const int base = (lane + w * 64) * 4;
        const float4 v = x[r][w];
        if (v.x > m[r]) { m[r] = v.x; am[r] = base + 0; }
        if (v.y > m[r]) { m[r] = v.y; am[r] = base + 1; }
        if (v.z > m[r]) { m[r] = v.z; am[r] = base + 2; }
        if (v.w > m[r]) { m[r] = v.w; am[r] = base + 3; }
      }
    }
    #pragma unroll
    for (int off = 32; off; off >>= 1) {
      #pragma unroll
      for (int r = 0; r < RPW; ++r) {
        const float om = __shfl_xor(m[r], off);
        const int oi = __shfl_xor(am[r], off);
        if (om > m[r] || (om == m[r] && oi < am[r])) { m[r] = om; am[r] = oi; }
      }
    }
    float s[RPW];
    #pragma unroll
    for (int r = 0; r < RPW; ++r) {
      s[r] = 0.f;
      #pragma unroll
      for (int w = 0; w < 4; ++w) {
        s[r] += __expf(x[r][w].x - m[r]) + __expf(x[r][w].y - m[r]) +
                __expf(x[r][w].z - m[r]) + __expf(x[r][w].w - m[r]);
      }
    }
    #pragma unroll
    for (int off = 32; off; off >>= 1) {
      #pragma unroll
      for (int r = 0; r < RPW; ++r) s[r] += __shfl_xor(s[r], off);
    }
    if (lane == 0) {
      #pragma unroll
      for (int r = 0; r < RPW; ++r) {
        const float p = 1.0f / s[r];
        const float v = ((tgt[rowbase + r] == am[r]) ? 1.0f : 0.0f) - p;
        float2 ab;
        ab.x = v * __expf(-p * KBW_INV);
        ab.y = v * __expf(p * KBW_INV);
        AB[rowbase + r] = ab;
      }
    }
  }

  cg::this_grid().sync();

  // ---------------- Phase 2: pairwise tiles, persistent over tiles ----------
  __shared__ float2 sj[JBLK];
  const int nTiles = (N / ICHUNK) * (N / JBLK);  // 1024
  const int nTJ = N / JBLK;                      // 128

  double dacc = 0.0;
  for (int t = blockIdx.x; t < nTiles; t += gridDim.x) {
    const int ti = t / nTJ;  // i-chunk of ICHUNK rows
    const int tj = t % nTJ;  // j-chunk of JBLK rows

    __syncthreads();  // protect sj against readers of the previous tile
    if (tid < JBLK) sj[tid] = AB[tj * JBLK + tid];

    float2 abi[IPT];
    #pragma unroll
    for (int u = 0; u < IPT; ++u)
      abi[u] = AB[ti * ICHUNK + u * TPB + tid];
    __syncthreads();

    float facc[IPT];
    #pragma unroll
    for (int u = 0; u < IPT; ++u) facc[u] = 0.f;

    #pragma unroll 8
    for (int jt = 0; jt < JBLK; ++jt) {
      const float aj = sj[jt].x;   // uniform jt -> LDS broadcast
      const float bj_ = sj[jt].y;
      #pragma unroll
      for (int u = 0; u < IPT; ++u) {
        const float xx = abi[u].x * bj_;
        const float yy = abi[u].y * aj;
        facc[u] += __builtin_amdgcn_fmed3f(xx, yy, 0.0f);
      }
    }
    dacc += (double)((facc[0] + facc[1]) + (facc[2] + facc[3]));
  }

  // ---------------- Fused deterministic reduction ---------------------------
  #pragma unroll
  for (int off = 32; off; off >>= 1) dacc += __shfl_xor(dacc, off);
  __shared__ double wsum[4];
  if ((tid & 63) == 0) wsum[tid >> 6] = dacc;
  __syncthreads();
  if (tid == 0) {
    const double blocksum = (wsum[0] + wsum[1]) + (wsum[2] + wsum[3]);
    const long long fx = __double2ll_rn(blocksum * FXSCALE);
    atomicAdd(acc, (unsigned long long)fx);  // integer adds: deterministic
    __threadfence();
    const unsigned int done = atomicAdd(counter, 1u);
    if (done == (unsigned int)nBlocks - 1u) {
      const unsigned long long total = atomicAdd(acc, 0ull);
      const double sum = (double)(long long)total * (1.0 / FXSCALE);
      out[0] = (float)(sum / ((double)N * (double)N));
    }
  }
}

extern "C" void kernel_launch(void* const* d_in, const int* in_sizes, int n_in,
                              void* d_out, int out_size, void* d_ws, size_t ws_size,
                              hipStream_t stream) {
  const float* inp = (const float*)d_in[0];
  const int* tgt = (const int*)d_in[1];
  int N = in_sizes[1];          // 8192
  int C = in_sizes[0] / N;      // 1000

  float2* AB = (float2*)d_ws;   // N float2
  unsigned long long* acc =
      (unsigned long long*)(((uintptr_t)(AB + N) + 15) & ~(uintptr_t)15);
  unsigned int* counter = (unsigned int*)(acc + 1);
  float* out = (float*)d_out;

  // Host-side occupancy clamp (pure host queries -- graph-capture safe,
  // deterministic). Never exceed what the runtime will co-schedule.
  int maxPerCU = 0;
  (void)hipOccupancyMaxActiveBlocksPerMultiprocessor(&maxPerCU, mmce_fused,
                                                     TPB, 0);
  if (maxPerCU < 1) maxPerCU = 1;
  int nCU = 0;
  (void)hipDeviceGetAttribute(&nCU, hipDeviceAttributeMultiprocessorCount, 0);
  if (nCU < 1) nCU = 256;

  int nBlocks = maxPerCU * nCU;
  const int nWork = N / GROUP;  // 1024 work units in each phase
  if (nBlocks > nWork) nBlocks = nWork;

  void* args[] = {&inp, &tgt, &AB, &acc, &counter, &out, &N, &C, &nBlocks};
  hipLaunchCooperativeKernel((const void*)mmce_fused, dim3(nBlocks), dim3(TPB),
                             args, 0, stream);
}

// Round 6
// 78.352 us; speedup vs baseline: 1.0083x; 1.0083x over previous
//
#include <hip/hip_runtime.h>
#include <math.h>
#include <stdint.h>

// MMCE: sum_{i,j} v_i v_j exp(-|p_i - p_j| / 0.4) / N^2
//   p_i = max softmax prob of row i, v_i = (argmax_i == target_i) - p_i.
// a_i = v_i e^{-p_i/bw}, b_i = v_i e^{+p_i/bw};
// pair term = med3(a_i*b_j, b_i*a_j, 0): both products share the sign of
// v_i*v_j; med3 picks min if positive, max if negative. 4 VALU/pair.
//
// R5 lesson: cg::this_grid().sync() costs ~55-85 us (system-scope fences +
// backoff spin, scaling with grid). Replaced by a lean agent-scope barrier;
// barrier/accumulator state is zeroed by a tiny hipMemsetAsync graph node
// before the kernel on every replay (no in-kernel reset races).

static constexpr float KBW_INV = 2.5f;           // 1/0.4
static constexpr double FXSCALE = 1073741824.0;  // 2^30 fixed-point

#define TPB 256
#define RPW 2        // rows per wave per group-iteration: 32 VGPR payload
#define GROUP 8      // rows per block per group-iteration (4 waves * RPW)
#define JBLK 64      // j-rows staged per tile
#define ICHUNK 1024  // i-rows per tile (IPT * TPB)
#define IPT 4

struct SyncState {         // zeroed by memset node each call
  unsigned int bar;        // barrier arrivals
  unsigned int gen;        // barrier release flag
  unsigned int counter;    // phase-2 completion count
  unsigned int pad;
  unsigned long long acc;  // fixed-point global sum
};

__global__ __launch_bounds__(TPB) void mmce_fused(
    const float* __restrict__ inp, const int* __restrict__ tgt,
    float2* __restrict__ AB, SyncState* st, float* __restrict__ out,
    int N, int C) {
  const int tid = threadIdx.x;
  const int wv = tid >> 6;
  const int lane = tid & 63;

  // ---------------- Phase 1: per-row stats, persistent over row-groups ------
  const int C4 = C >> 2;  // 250 float4 per row
  const int nGroups = N / GROUP;

  for (int g = blockIdx.x; g < nGroups; g += gridDim.x) {
    const int rowbase = g * GROUP + wv * RPW;

    float4 x[RPW][4];
    #pragma unroll
    for (int r = 0; r < RPW; ++r) {
      const float4* rp =
          reinterpret_cast<const float4*>(inp + (size_t)(rowbase + r) * C);
      #pragma unroll
      for (int w = 0; w < 4; ++w) {
        const int k = lane + w * 64;
        x[r][w] = (k < C4)
                      ? rp[k]
                      : make_float4(-INFINITY, -INFINITY, -INFINITY, -INFINITY);
      }
    }

    float m[RPW];
    int am[RPW];
    #pragma unroll
    for (int r = 0; r < RPW; ++r) {
      m[r] = -INFINITY;
      am[r] = 0x7fffffff;
      #pragma unroll
      for (int w = 0; w < 4; ++w) {
        const int base = (lane + w * 64) * 4;
        const float4 v = x[r][w];
        if (v.x > m[r]) { m[r] = v.x; am[r] = base + 0; }
        if (v.y > m[r]) { m[r] = v.y; am[r] = base + 1; }
        if (v.z > m[r]) { m[r] = v.z; am[r] = base + 2; }
        if (v.w > m[r]) { m[r] = v.w; am[r] = base + 3; }
      }
    }
    #pragma unroll
    for (int off = 32; off; off >>= 1) {
      #pragma unroll
      for (int r = 0; r < RPW; ++r) {
        const float om = __shfl_xor(m[r], off);
        const int oi = __shfl_xor(am[r], off);
        if (om > m[r] || (om == m[r] && oi < am[r])) { m[r] = om; am[r] = oi; }
      }
    }
    float s[RPW];
    #pragma unroll
    for (int r = 0; r < RPW; ++r) {
      s[r] = 0.f;
      #pragma unroll
      for (int w = 0; w < 4; ++w) {
        s[r] += __expf(x[r][w].x - m[r]) + __expf(x[r][w].y - m[r]) +
                __expf(x[r][w].z - m[r]) + __expf(x[r][w].w - m[r]);
      }
    }
    #pragma unroll
    for (int off = 32; off; off >>= 1) {
      #pragma unroll
      for (int r = 0; r < RPW; ++r) s[r] += __shfl_xor(s[r], off);
    }
    if (lane == 0) {
      #pragma unroll
      for (int r = 0; r < RPW; ++r) {
        const float p = 1.0f / s[r];
        const float v = ((tgt[rowbase + r] == am[r]) ? 1.0f : 0.0f) - p;
        float2 ab;
        ab.x = v * __expf(-p * KBW_INV);
        ab.y = v * __expf(p * KBW_INV);
        AB[rowbase + r] = ab;
      }
    }
  }

  // ---------------- Lean grid barrier (agent scope) -------------------------
  __syncthreads();
  if (tid == 0) {
    __builtin_amdgcn_fence(__ATOMIC_RELEASE, "agent");  // AB visible at L3
    const unsigned int t = __hip_atomic_fetch_add(
        &st->bar, 1u, __ATOMIC_RELAXED, __HIP_MEMORY_SCOPE_AGENT);
    if (t == gridDim.x - 1u) {
      __hip_atomic_store(&st->gen, 1u, __ATOMIC_RELAXED,
                         __HIP_MEMORY_SCOPE_AGENT);
    } else {
      while (__hip_atomic_load(&st->gen, __ATOMIC_RELAXED,
                               __HIP_MEMORY_SCOPE_AGENT) == 0u)
        __builtin_amdgcn_s_sleep(1);
    }
    __builtin_amdgcn_fence(__ATOMIC_ACQUIRE, "agent");  // drop stale L1/L2
  }
  __syncthreads();

  // ---------------- Phase 2: pairwise tiles, persistent over tiles ----------
  __shared__ float2 sj[JBLK];
  const int nTiles = (N / ICHUNK) * (N / JBLK);  // 1024
  const int nTJ = N / JBLK;                      // 128

  double dacc = 0.0;
  for (int t = blockIdx.x; t < nTiles; t += gridDim.x) {
    const int ti = t / nTJ;
    const int tj = t % nTJ;

    __syncthreads();  // protect sj against readers of the previous tile
    if (tid < JBLK) sj[tid] = AB[tj * JBLK + tid];

    float2 abi[IPT];
    #pragma unroll
    for (int u = 0; u < IPT; ++u)
      abi[u] = AB[ti * ICHUNK + u * TPB + tid];
    __syncthreads();

    float facc[IPT];
    #pragma unroll
    for (int u = 0; u < IPT; ++u) facc[u] = 0.f;

    #pragma unroll 8
    for (int jt = 0; jt < JBLK; ++jt) {
      const float aj = sj[jt].x;   // uniform jt -> LDS broadcast
      const float bj_ = sj[jt].y;
      #pragma unroll
      for (int u = 0; u < IPT; ++u) {
        const float xx = abi[u].x * bj_;
        const float yy = abi[u].y * aj;
        facc[u] += __builtin_amdgcn_fmed3f(xx, yy, 0.0f);
      }
    }
    dacc += (double)((facc[0] + facc[1]) + (facc[2] + facc[3]));
  }

  // ---------------- Fused deterministic reduction ---------------------------
  #pragma unroll
  for (int off = 32; off; off >>= 1) dacc += __shfl_xor(dacc, off);
  __shared__ double wsum[4];
  if ((tid & 63) == 0) wsum[tid >> 6] = dacc;
  __syncthreads();
  if (tid == 0) {
    const double blocksum = (wsum[0] + wsum[1]) + (wsum[2] + wsum[3]);
    const long long fx = __double2ll_rn(blocksum * FXSCALE);
    atomicAdd(&st->acc, (unsigned long long)fx);  // integer: deterministic
    __threadfence();
    const unsigned int done = atomicAdd(&st->counter, 1u);
    if (done == gridDim.x - 1u) {
      const unsigned long long total = atomicAdd(&st->acc, 0ull);
      const double sum = (double)(long long)total * (1.0 / FXSCALE);
      out[0] = (float)(sum / ((double)N * (double)N));
    }
  }
}

extern "C" void kernel_launch(void* const* d_in, const int* in_sizes, int n_in,
                              void* d_out, int out_size, void* d_ws, size_t ws_size,
                              hipStream_t stream) {
  const float* inp = (const float*)d_in[0];
  const int* tgt = (const int*)d_in[1];
  int N = in_sizes[1];          // 8192
  int C = in_sizes[0] / N;      // 1000

  SyncState* st = (SyncState*)d_ws;                      // 64B, zeroed below
  float2* AB = (float2*)((char*)d_ws + 64);              // N float2
  float* out = (float*)d_out;

  // Zero barrier/accumulator state every call (graph-capturable memset node).
  hipMemsetAsync(d_ws, 0, 64, stream);

  // Host-side occupancy clamp (pure host queries -- capture safe).
  int maxPerCU = 0;
  (void)hipOccupancyMaxActiveBlocksPerMultiprocessor(&maxPerCU, mmce_fused,
                                                     TPB, 0);
  if (maxPerCU < 1) maxPerCU = 1;
  int nCU = 0;
  (void)hipDeviceGetAttribute(&nCU, hipDeviceAttributeMultiprocessorCount, 0);
  if (nCU < 1) nCU = 256;

  int nBlocks = maxPerCU * nCU;
  const int nWork = N / GROUP;  // 1024 work units in each phase
  if (nBlocks > nWork) nBlocks = nWork;

  void* args[] = {&inp, &tgt, &AB, &st, &out, &N, &C};
  hipLaunchCooperativeKernel((const void*)mmce_fused, dim3(nBlocks), dim3(TPB),
                             args, 0, stream);
}

// Round 10
// 62.225 us; speedup vs baseline: 1.2696x; 1.2592x over previous
//
#include <hip/hip_runtime.h>
#include <math.h>
#include <stdint.h>

// MMCE: sum_{i,j} v_i v_j exp(-|p_i - p_j| / 0.4) / N^2
//   p_i = max softmax prob of row i, v_i = (argmax_i == target_i) - p_i.
// a_i = v_i e^{-p_i/bw}, b_i = v_i e^{+p_i/bw};
// pair term = med3(a_i*b_j, b_i*a_j, 0): both products share the sign of
// v_i*v_j; med3 picks min if positive, max if negative. 4 VALU/pair.
//
// R6 lesson: hipLaunchCooperativeKernel itself costs ~50-65 us fixed on
// MI355X (wall identical across 512/1024-block grids and CG-vs-custom
// barriers; VALU work only ~9 us). Same kernel now uses a NORMAL launch
// at grid=512 (2 blocks/CU; capacity >= 8 blocks/CU at 52 VGPR / 1 KB LDS,
// so co-residency holds) with the proven hand-rolled grid barrier.
// (R7/R8/R9 were infra failures -- same kernel resubmitted.)

static constexpr float KBW_INV = 2.5f;           // 1/0.4
static constexpr double FXSCALE = 1073741824.0;  // 2^30 fixed-point

#define TPB 256
#define GRID 512     // 2 blocks/CU on 256 CUs; all co-resident at launch
#define RPW 2        // rows per wave per group-iteration: 32 VGPR payload
#define GROUP 8      // rows per block per group-iteration (4 waves * RPW)
#define JBLK 64      // j-rows staged per tile
#define ICHUNK 1024  // i-rows per tile (IPT * TPB)
#define IPT 4

struct SyncState {         // zeroed by memset node each call
  unsigned int bar;        // barrier arrivals
  unsigned int gen;        // barrier release flag
  unsigned int counter;    // phase-2 completion count
  unsigned int pad;
  unsigned long long acc;  // fixed-point global sum
};

__global__ __launch_bounds__(TPB) void mmce_fused(
    const float* __restrict__ inp, const int* __restrict__ tgt,
    float2* __restrict__ AB, SyncState* st, float* __restrict__ out,
    int N, int C) {
  const int tid = threadIdx.x;
  const int wv = tid >> 6;
  const int lane = tid & 63;

  // ---------------- Phase 1: per-row stats, persistent over row-groups ------
  const int C4 = C >> 2;  // 250 float4 per row
  const int nGroups = N / GROUP;  // 1024 -> 2 iterations per block

  for (int g = blockIdx.x; g < nGroups; g += GRID) {
    const int rowbase = g * GROUP + wv * RPW;

    float4 x[RPW][4];
    #pragma unroll
    for (int r = 0; r < RPW; ++r) {
      const float4* rp =
          reinterpret_cast<const float4*>(inp + (size_t)(rowbase + r) * C);
      #pragma unroll
      for (int w = 0; w < 4; ++w) {
        const int k = lane + w * 64;
        x[r][w] = (k < C4)
                      ? rp[k]
                      : make_float4(-INFINITY, -INFINITY, -INFINITY, -INFINITY);
      }
    }

    float m[RPW];
    int am[RPW];
    #pragma unroll
    for (int r = 0; r < RPW; ++r) {
      m[r] = -INFINITY;
      am[r] = 0x7fffffff;
      #pragma unroll
      for (int w = 0; w < 4; ++w) {
        const int base = (lane + w * 64) * 4;
        const float4 v = x[r][w];
        if (v.x > m[r]) { m[r] = v.x; am[r] = base + 0; }
        if (v.y > m[r]) { m[r] = v.y; am[r] = base + 1; }
        if (v.z > m[r]) { m[r] = v.z; am[r] = base + 2; }
        if (v.w > m[r]) { m[r] = v.w; am[r] = base + 3; }
      }
    }
    #pragma unroll
    for (int off = 32; off; off >>= 1) {
      #pragma unroll
      for (int r = 0; r < RPW; ++r) {
        const float om = __shfl_xor(m[r], off);
        const int oi = __shfl_xor(am[r], off);
        if (om > m[r] || (om == m[r] && oi < am[r])) { m[r] = om; am[r] = oi; }
      }
    }
    float s[RPW];
    #pragma unroll
    for (int r = 0; r < RPW; ++r) {
      s[r] = 0.f;
      #pragma unroll
      for (int w = 0; w < 4; ++w) {
        s[r] += __expf(x[r][w].x - m[r]) + __expf(x[r][w].y - m[r]) +
                __expf(x[r][w].z - m[r]) + __expf(x[r][w].w - m[r]);
      }
    }
    #pragma unroll
    for (int off = 32; off; off >>= 1) {
      #pragma unroll
      for (int r = 0; r < RPW; ++r) s[r] += __shfl_xor(s[r], off);
    }
    if (lane == 0) {
      #pragma unroll
      for (int r = 0; r < RPW; ++r) {
        const float p = 1.0f / s[r];
        const float v = ((tgt[rowbase + r] == am[r]) ? 1.0f : 0.0f) - p;
        float2 ab;
        ab.x = v * __expf(-p * KBW_INV);
        ab.y = v * __expf(p * KBW_INV);
        AB[rowbase + r] = ab;
      }
    }
  }

  // ---------------- Lean grid barrier (agent scope) -------------------------
  __syncthreads();
  if (tid == 0) {
    __builtin_amdgcn_fence(__ATOMIC_RELEASE, "agent");  // AB visible at L3
    const unsigned int t = __hip_atomic_fetch_add(
        &st->bar, 1u, __ATOMIC_RELAXED, __HIP_MEMORY_SCOPE_AGENT);
    if (t == (unsigned int)GRID - 1u) {
      __hip_atomic_store(&st->gen, 1u, __ATOMIC_RELAXED,
                         __HIP_MEMORY_SCOPE_AGENT);
    } else {
      while (__hip_atomic_load(&st->gen, __ATOMIC_RELAXED,
                               __HIP_MEMORY_SCOPE_AGENT) == 0u)
        __builtin_amdgcn_s_sleep(1);
    }
    __builtin_amdgcn_fence(__ATOMIC_ACQUIRE, "agent");  // drop stale L1/L2
  }
  __syncthreads();

  // ---------------- Phase 2: pairwise tiles, persistent over tiles ----------
  __shared__ float2 sj[JBLK];
  const int nTiles = (N / ICHUNK) * (N / JBLK);  // 1024 -> 2 per block
  const int nTJ = N / JBLK;                      // 128

  double dacc = 0.0;
  for (int t = blockIdx.x; t < nTiles; t += GRID) {
    const int ti = t / nTJ;
    const int tj = t % nTJ;

    __syncthreads();  // protect sj against readers of the previous tile
    if (tid < JBLK) sj[tid] = AB[tj * JBLK + tid];

    float2 abi[IPT];
    #pragma unroll
    for (int u = 0; u < IPT; ++u)
      abi[u] = AB[ti * ICHUNK + u * TPB + tid];
    __syncthreads();

    float facc[IPT];
    #pragma unroll
    for (int u = 0; u < IPT; ++u) facc[u] = 0.f;

    #pragma unroll 8
    for (int jt = 0; jt < JBLK; ++jt) {
      const float aj = sj[jt].x;   // uniform jt -> LDS broadcast
      const float bj_ = sj[jt].y;
      #pragma unroll
      for (int u = 0; u < IPT; ++u) {
        const float xx = abi[u].x * bj_;
        const float yy = abi[u].y * aj;
        facc[u] += __builtin_amdgcn_fmed3f(xx, yy, 0.0f);
      }
    }
    dacc += (double)((facc[0] + facc[1]) + (facc[2] + facc[3]));
  }

  // ---------------- Fused deterministic reduction ---------------------------
  #pragma unroll
  for (int off = 32; off; off >>= 1) dacc += __shfl_xor(dacc, off);
  __shared__ double wsum[4];
  if ((tid & 63) == 0) wsum[tid >> 6] = dacc;
  __syncthreads();
  if (tid == 0) {
    const double blocksum = (wsum[0] + wsum[1]) + (wsum[2] + wsum[3]);
    const long long fx = __double2ll_rn(blocksum * FXSCALE);
    atomicAdd(&st->acc, (unsigned long long)fx);  // integer: deterministic
    __threadfence();
    const unsigned int done = atomicAdd(&st->counter, 1u);
    if (done == (unsigned int)GRID - 1u) {
      const unsigned long long total = atomicAdd(&st->acc, 0ull);
      const double sum = (double)(long long)total * (1.0 / FXSCALE);
      out[0] = (float)(sum / ((double)N * (double)N));
    }
  }
}

extern "C" void kernel_launch(void* const* d_in, const int* in_sizes, int n_in,
                              void* d_out, int out_size, void* d_ws, size_t ws_size,
                              hipStream_t stream) {
  const float* inp = (const float*)d_in[0];
  const int* tgt = (const int*)d_in[1];
  int N = in_sizes[1];          // 8192
  int C = in_sizes[0] / N;      // 1000

  SyncState* st = (SyncState*)d_ws;          // 64B, zeroed below
  float2* AB = (float2*)((char*)d_ws + 64);  // N float2
  float* out = (float*)d_out;

  // Zero barrier/accumulator state every call (graph-capturable memset node).
  hipMemsetAsync(d_ws, 0, 64, stream);

  mmce_fused<<<GRID, TPB, 0, stream>>>(inp, tgt, AB, st, out, N, C);
}

// Round 11
// 36.069 us; speedup vs baseline: 2.1904x; 1.7252x over previous
//
#include <hip/hip_runtime.h>
#include <math.h>
#include <stdint.h>

// MMCE: sum_{i,j} v_i v_j exp(-|p_i - p_j| / 0.4) / N^2
//   p_i = max softmax prob of row i, v_i = (argmax_i == target_i) - p_i.
// a_i = v_i e^{-p_i/bw}, b_i = v_i e^{+p_i/bw};
// pair term = med3(a_i*b_j, b_i*a_j, 0): both products share the sign of
// v_i*v_j; med3 picks min if positive, max if negative. 4 VALU/pair.
//
// R10 lesson: the fused persistent kernel idles ~50 us in-kernel (VALUBusy
// 14.5% of 58 us; not BW-bound) regardless of launch type. Reverting to two
// plain kernels (no grid barrier) to isolate: K1 = R1's proven rowstats at
// 2048 blocks (1 row/wave, full occupancy), K2 = R2's pairwise with the
// final reduction fused via fixed-point atomics (proven deterministic).

#define WAVE 64
static constexpr float KBW_INV = 2.5f;           // 1/0.4
static constexpr double FXSCALE = 1073741824.0;  // 2^30 fixed-point

struct SyncState {         // zeroed by memset node each call
  unsigned int counter;    // K2 completion count
  unsigned int pad;
  unsigned long long acc;  // fixed-point global sum
};

// ---------------- Kernel 1: per-row softmax-max stats (1 wave per row) ----
__global__ __launch_bounds__(256) void rowstats_kernel(
    const float* __restrict__ inp, const int* __restrict__ tgt,
    float2* __restrict__ AB, int N, int C) {
  const int wave = threadIdx.x >> 6;
  const int lane = threadIdx.x & 63;
  const int row = blockIdx.x * 4 + wave;
  if (row >= N) return;
  const int C4 = C >> 2;  // 250 float4 per row
  const float4* rp = reinterpret_cast<const float4*>(inp + (size_t)row * C);

  // Whole row in registers: 4 float4 per lane (16 VGPR payload).
  float4 x[4];
  bool valid[4];
  float m = -INFINITY;
  int am = 0x7fffffff;
  #pragma unroll
  for (int w = 0; w < 4; ++w) {
    const int k = lane + w * WAVE;
    valid[w] = (k < C4);
    if (valid[w]) {
      float4 v = rp[k];
      x[w] = v;
      const int base = k * 4;
      // increasing index order + strict '>' keeps first occurrence
      if (v.x > m) { m = v.x; am = base + 0; }
      if (v.y > m) { m = v.y; am = base + 1; }
      if (v.z > m) { m = v.z; am = base + 2; }
      if (v.w > m) { m = v.w; am = base + 3; }
    }
  }
  // Wave reduce (max, argmax) with first-index tie-break.
  #pragma unroll
  for (int off = 32; off; off >>= 1) {
    float om = __shfl_xor(m, off);
    int oi = __shfl_xor(am, off);
    if (om > m || (om == m && oi < am)) { m = om; am = oi; }
  }
  // Sum of exp(x - m) over the row.
  float s = 0.f;
  #pragma unroll
  for (int w = 0; w < 4; ++w) {
    if (valid[w]) {
      s += __expf(x[w].x - m) + __expf(x[w].y - m) +
           __expf(x[w].z - m) + __expf(x[w].w - m);
    }
  }
  #pragma unroll
  for (int off = 32; off; off >>= 1) s += __shfl_xor(s, off);

  if (lane == 0) {
    const float p = 1.0f / s;
    const float v = ((tgt[row] == am) ? 1.0f : 0.0f) - p;
    float2 ab;
    ab.x = v * __expf(-p * KBW_INV);  // a_i
    ab.y = v * __expf(p * KBW_INV);   // b_i
    AB[row] = ab;
  }
}

// ---------------- Kernel 2: pairwise sum + fused final reduction ----------
#define JBLK 128   // j-rows staged per block
#define IPT 4      // i-rows per thread
// grid = (N/(256*IPT)) * (N/JBLK) = 8 * 64 = 512 blocks

__global__ __launch_bounds__(256) void pairwise_kernel(
    const float2* __restrict__ AB, SyncState* st, float* __restrict__ out,
    int N, int nBlocks) {
  __shared__ float2 sj[JBLK];
  const int nJB = N / JBLK;          // 64
  const int bi = blockIdx.x / nJB;   // 0..7  (i-chunk of 1024 rows)
  const int bj = blockIdx.x % nJB;   // 0..63 (j-chunk of 128 rows)
  const int tid = threadIdx.x;

  if (tid < JBLK) sj[tid] = AB[bj * JBLK + tid];

  float2 abi[IPT];
  #pragma unroll
  for (int u = 0; u < IPT; ++u) abi[u] = AB[bi * (256 * IPT) + u * 256 + tid];
  __syncthreads();

  float facc[IPT];
  #pragma unroll
  for (int u = 0; u < IPT; ++u) facc[u] = 0.f;

  #pragma unroll 8
  for (int t = 0; t < JBLK; ++t) {
    const float aj = sj[t].x;   // uniform t -> LDS broadcast, conflict-free
    const float bj_ = sj[t].y;
    #pragma unroll
    for (int u = 0; u < IPT; ++u) {
      const float xx = abi[u].x * bj_;  // a_i * b_j
      const float yy = abi[u].y * aj;   // b_i * a_j
      facc[u] += __builtin_amdgcn_fmed3f(xx, yy, 0.0f);
    }
  }

  double dacc = (double)((facc[0] + facc[1]) + (facc[2] + facc[3]));
  #pragma unroll
  for (int off = 32; off; off >>= 1) dacc += __shfl_xor(dacc, off);
  __shared__ double wsum[4];
  if ((tid & 63) == 0) wsum[tid >> 6] = dacc;
  __syncthreads();
  if (tid == 0) {
    const double blocksum = (wsum[0] + wsum[1]) + (wsum[2] + wsum[3]);
    const long long fx = __double2ll_rn(blocksum * FXSCALE);
    atomicAdd(&st->acc, (unsigned long long)fx);  // integer: deterministic
    __threadfence();
    const unsigned int done = atomicAdd(&st->counter, 1u);
    if (done == (unsigned int)nBlocks - 1u) {
      const unsigned long long total = atomicAdd(&st->acc, 0ull);
      const double sum = (double)(long long)total * (1.0 / FXSCALE);
      out[0] = (float)(sum / ((double)N * (double)N));
    }
  }
}

extern "C" void kernel_launch(void* const* d_in, const int* in_sizes, int n_in,
                              void* d_out, int out_size, void* d_ws, size_t ws_size,
                              hipStream_t stream) {
  const float* inp = (const float*)d_in[0];
  const int* tgt = (const int*)d_in[1];
  const int N = in_sizes[1];             // 8192
  const int C = in_sizes[0] / N;         // 1000

  SyncState* st = (SyncState*)d_ws;          // 64B, zeroed below
  float2* AB = (float2*)((char*)d_ws + 64);  // N float2
  float* out = (float*)d_out;

  // Zero accumulator state every call (graph-capturable memset node).
  hipMemsetAsync(d_ws, 0, 64, stream);

  const int rowBlocks = (N + 3) / 4;     // 2048 blocks, 4 waves, 1 row/wave
  rowstats_kernel<<<rowBlocks, 256, 0, stream>>>(inp, tgt, AB, N, C);

  const int nIB = N / (256 * IPT);       // 8
  const int nJB = N / JBLK;              // 64
  const int nPair = nIB * nJB;           // 512 blocks
  pairwise_kernel<<<nPair, 256, 0, stream>>>(AB, st, out, N, nPair);
}

// Round 12
// 30.862 us; speedup vs baseline: 2.5599x; 1.1687x over previous
//
#include <hip/hip_runtime.h>
#include <math.h>
#include <stdint.h>

// MMCE: sum_{i,j} v_i v_j exp(-|p_i - p_j| / 0.4) / N^2
//   p_i = max softmax prob of row i, v_i = (argmax_i == target_i) - p_i.
// a_i = v_i e^{-p_i/bw}, b_i = v_i e^{+p_i/bw};
// pair term = med3(a_i*b_j, b_i*a_j, 0): both products share the sign of
// v_i*v_j; med3 picks min if positive, max if negative. 4 VALU/pair.
//
// R11 lesson: a 64-byte hipMemsetAsync graph node costs ~5.6 us on this
// runtime (R2=30.5 us without it, R11=36.1 us with it; tiny fillBuffer
// dispatches show ~41 us in rocprof). State zeroing is folded back into
// K1 block 0 (race-free: K1 retires before K2 dispatches). 2 graph nodes.

#define WAVE 64
static constexpr float KBW_INV = 2.5f;           // 1/0.4
static constexpr double FXSCALE = 1073741824.0;  // 2^30 fixed-point

struct SyncState {         // zeroed by K1 block 0 each call
  unsigned int counter;    // K2 completion count
  unsigned int pad;
  unsigned long long acc;  // fixed-point global sum
};

// ---------------- Kernel 1: per-row softmax-max stats (1 wave per row) ----
__global__ __launch_bounds__(256) void rowstats_kernel(
    const float* __restrict__ inp, const int* __restrict__ tgt,
    float2* __restrict__ AB, SyncState* st, int N, int C) {
  if (blockIdx.x == 0 && threadIdx.x == 0) {
    st->counter = 0u;
    st->acc = 0ull;
  }
  const int wave = threadIdx.x >> 6;
  const int lane = threadIdx.x & 63;
  const int row = blockIdx.x * 4 + wave;
  if (row >= N) return;
  const int C4 = C >> 2;  // 250 float4 per row
  const float4* rp = reinterpret_cast<const float4*>(inp + (size_t)row * C);

  // Whole row in registers: 4 float4 per lane (16 VGPR payload).
  float4 x[4];
  bool valid[4];
  float m = -INFINITY;
  int am = 0x7fffffff;
  #pragma unroll
  for (int w = 0; w < 4; ++w) {
    const int k = lane + w * WAVE;
    valid[w] = (k < C4);
    if (valid[w]) {
      float4 v = rp[k];
      x[w] = v;
      const int base = k * 4;
      // increasing index order + strict '>' keeps first occurrence
      if (v.x > m) { m = v.x; am = base + 0; }
      if (v.y > m) { m = v.y; am = base + 1; }
      if (v.z > m) { m = v.z; am = base + 2; }
      if (v.w > m) { m = v.w; am = base + 3; }
    }
  }
  // Wave reduce (max, argmax) with first-index tie-break.
  #pragma unroll
  for (int off = 32; off; off >>= 1) {
    float om = __shfl_xor(m, off);
    int oi = __shfl_xor(am, off);
    if (om > m || (om == m && oi < am)) { m = om; am = oi; }
  }
  // Sum of exp(x - m) over the row.
  float s = 0.f;
  #pragma unroll
  for (int w = 0; w < 4; ++w) {
    if (valid[w]) {
      s += __expf(x[w].x - m) + __expf(x[w].y - m) +
           __expf(x[w].z - m) + __expf(x[w].w - m);
    }
  }
  #pragma unroll
  for (int off = 32; off; off >>= 1) s += __shfl_xor(s, off);

  if (lane == 0) {
    const float p = 1.0f / s;
    const float v = ((tgt[row] == am) ? 1.0f : 0.0f) - p;
    float2 ab;
    ab.x = v * __expf(-p * KBW_INV);  // a_i
    ab.y = v * __expf(p * KBW_INV);   // b_i
    AB[row] = ab;
  }
}

// ---------------- Kernel 2: pairwise sum + fused final reduction ----------
#define JBLK 128   // j-rows staged per block
#define IPT 4      // i-rows per thread
// grid = (N/(256*IPT)) * (N/JBLK) = 8 * 64 = 512 blocks

__global__ __launch_bounds__(256) void pairwise_kernel(
    const float2* __restrict__ AB, SyncState* st, float* __restrict__ out,
    int N, int nBlocks) {
  __shared__ float2 sj[JBLK];
  const int nJB = N / JBLK;          // 64
  const int bi = blockIdx.x / nJB;   // 0..7  (i-chunk of 1024 rows)
  const int bj = blockIdx.x % nJB;   // 0..63 (j-chunk of 128 rows)
  const int tid = threadIdx.x;

  if (tid < JBLK) sj[tid] = AB[bj * JBLK + tid];

  float2 abi[IPT];
  #pragma unroll
  for (int u = 0; u < IPT; ++u) abi[u] = AB[bi * (256 * IPT) + u * 256 + tid];
  __syncthreads();

  float facc[IPT];
  #pragma unroll
  for (int u = 0; u < IPT; ++u) facc[u] = 0.f;

  #pragma unroll 8
  for (int t = 0; t < JBLK; ++t) {
    const float aj = sj[t].x;   // uniform t -> LDS broadcast, conflict-free
    const float bj_ = sj[t].y;
    #pragma unroll
    for (int u = 0; u < IPT; ++u) {
      const float xx = abi[u].x * bj_;  // a_i * b_j
      const float yy = abi[u].y * aj;   // b_i * a_j
      facc[u] += __builtin_amdgcn_fmed3f(xx, yy, 0.0f);
    }
  }

  double dacc = (double)((facc[0] + facc[1]) + (facc[2] + facc[3]));
  #pragma unroll
  for (int off = 32; off; off >>= 1) dacc += __shfl_xor(dacc, off);
  __shared__ double wsum[4];
  if ((tid & 63) == 0) wsum[tid >> 6] = dacc;
  __syncthreads();
  if (tid == 0) {
    const double blocksum = (wsum[0] + wsum[1]) + (wsum[2] + wsum[3]);
    const long long fx = __double2ll_rn(blocksum * FXSCALE);
    atomicAdd(&st->acc, (unsigned long long)fx);  // integer: deterministic
    __threadfence();
    const unsigned int done = atomicAdd(&st->counter, 1u);
    if (done == (unsigned int)nBlocks - 1u) {
      const unsigned long long total = atomicAdd(&st->acc, 0ull);
      const double sum = (double)(long long)total * (1.0 / FXSCALE);
      out[0] = (float)(sum / ((double)N * (double)N));
    }
  }
}

extern "C" void kernel_launch(void* const* d_in, const int* in_sizes, int n_in,
                              void* d_out, int out_size, void* d_ws, size_t ws_size,
                              hipStream_t stream) {
  const float* inp = (const float*)d_in[0];
  const int* tgt = (const int*)d_in[1];
  const int N = in_sizes[1];             // 8192
  const int C = in_sizes[0] / N;         // 1000

  SyncState* st = (SyncState*)d_ws;          // zeroed by K1 block 0
  float2* AB = (float2*)((char*)d_ws + 64);  // N float2
  float* out = (float*)d_out;

  const int rowBlocks = (N + 3) / 4;     // 2048 blocks, 4 waves, 1 row/wave
  rowstats_kernel<<<rowBlocks, 256, 0, stream>>>(inp, tgt, AB, st, N, C);

  const int nIB = N / (256 * IPT);       // 8
  const int nJB = N / JBLK;              // 64
  const int nPair = nIB * nJB;           // 512 blocks
  pairwise_kernel<<<nPair, 256, 0, stream>>>(AB, st, out, N, nPair);
}